// Round 2
// 1427.073 us; speedup vs baseline: 1.0950x; 1.0950x over previous
//
#include <hip/hip_runtime.h>
#include <math.h>

typedef unsigned short U16;
typedef unsigned int   U32;
typedef __attribute__((ext_vector_type(8))) __bf16 bf16x8;
typedef __attribute__((ext_vector_type(4))) float  f32x4;

__device__ __forceinline__ U16 f2bf(float f) {
    __bf16 h = (__bf16)f;
    return __builtin_bit_cast(U16, h);
}
__device__ __forceinline__ float gelu_f(float y) {
    return 0.5f * y * (1.0f + erff(y * 0.70710678118654752f));
}

#define XT_S  69     // fp32 x-tile row stride (68 cols + 1 pad)
#define XT_CS 207    // 3 * XT_S, per-channel stride
#define ELS   40     // El per-pixel channel stride (32 ch + 8 pad) -> 80 B, 16B-aligned

// ---------------- K0: one-time weight fp32 -> bf16 conversion ----------------
__global__ void k0_cvt(const float* __restrict__ wB, const float* __restrict__ wf,
                       U16* __restrict__ wBb, U16* __restrict__ wfb)
{
    const int i = blockIdx.x * 256 + threadIdx.x;   // 1024 blocks -> 262144 = both sizes
    wBb[i] = f2bf(wB[i]);
    wfb[i] = f2bf(wf[i]);
}

// ---------------- K1: edge maps + 4 branch GEMMs + BN + GELU + pooled ----------------
// ef layout [b][c][pix] (== output layout, lives in d_out).
// Epilogue stores are restaged via per-wave LDS so every global store instruction is
// one full-wave-contiguous 256 B row segment (fixes 17x write amplification).
__global__ __launch_bounds__(256, 2)
void k1_branch(const float* __restrict__ x, const U16* __restrict__ wBb,
               const float* __restrict__ bB, const float* __restrict__ bg,
               const float* __restrict__ bbt, float* __restrict__ ef,
               float* __restrict__ pooled)
{
    __shared__ __align__(16) char smem[46976];
    float* xs  = (float*)smem;                 // 32*207 fp32 = 26496 B
    U16*   El  = (U16*)(smem + 26496);         // 4*64*40 U16 = 20480 B
    float* stg = (float*)(smem + 26496);       // epilogue: aliases El (dead after k-loop)

    const int tid  = threadIdx.x;
    // bijective chunked XCD swizzle: dispatch p -> XCD p%8; give each XCD a
    // contiguous 128-block chunk so h-adjacent blocks share an L2 (halo reuse).
    const int bi   = ((blockIdx.x & 7) << 7) | (blockIdx.x >> 3);
    const int b    = bi >> 8;
    const int rem  = bi & 255;
    const int h    = rem >> 1;
    const int w0   = (rem & 1) << 6;
    const int lane = tid & 63;
    const int wv   = tid >> 6;          // wave = branch id (sobel,lap,diag,grad)
    const int l15  = lane & 15;
    const int quad = lane >> 4;
    const int ec   = tid & 31;          // E-compute: channel within chunk
    const int px0  = (tid >> 5) * 8;    // E-compute: 8-pixel group

    f32x4 acc[8][4];
#pragma unroll
    for (int i = 0; i < 8; ++i)
#pragma unroll
        for (int j = 0; j < 4; ++j) {
            f32x4 z = {0.f, 0.f, 0.f, 0.f};
            acc[i][j] = z;
        }

#pragma unroll 1
    for (int ch = 0; ch < 16; ++ch) {
        const int cbase = ch * 32;
        // ---- stage x tile: 32 ch x 3 rows x 68 cols, fp32 ----
        for (int i = tid; i < 6528; i += 256) {
            int c  = i / 204;
            int r2 = i - c * 204;
            int r  = r2 / 68;
            int d  = r2 - r * 68;
            int hg  = h + r - 1;
            int col = w0 - 2 + d;
            float val = 0.f;
            if (hg >= 0 && hg < 128 && col >= 0 && col < 128)
                val = x[(((b * 512 + cbase + c) * 128 + hg) << 7) + col];
            xs[c * XT_CS + r * XT_S + d] = val;
        }
        __syncthreads();
        // ---- compute E (sobel, lap, diag, grad) in fp32 -> El bf16 ----
        {
            const int base = ec * XT_CS;
#pragma unroll 1
            for (int i = 0; i < 8; ++i) {
                const int px = px0 + i;
                float v[3][3];
#pragma unroll
                for (int r = 0; r < 3; ++r)
#pragma unroll
                    for (int jj = 0; jj < 3; ++jj)
                        v[r][jj] = xs[base + r * XT_S + px + 1 + jj];
                float gh = (v[0][2] - v[0][0]) + 2.f * (v[1][2] - v[1][0]) + (v[2][2] - v[2][0]);
                float gv = (v[2][0] + 2.f * v[2][1] + v[2][2]) - (v[0][0] + 2.f * v[0][1] + v[0][2]);
                float lp = v[0][1] + v[1][0] + v[1][2] + v[2][1] - 4.f * v[1][1];
                float d1 = v[0][0] - v[0][2] - v[2][0] + v[2][2];
                float sob = sqrtf(gh * gh + gv * gv + 1e-8f);
                float lav = fabsf(lp);
                float dia = fabsf(d1);   // K_D2 == -K_D1 -> max(|d1|,|d2|) = |d1|
                float grd = sqrtf(sob * sob + lav * lav + 1e-8f);
                El[(0 * 64 + px) * ELS + ec] = f2bf(sob);
                El[(1 * 64 + px) * ELS + ec] = f2bf(lav);
                El[(2 * 64 + px) * ELS + ec] = f2bf(dia);
                El[(3 * 64 + px) * ELS + ec] = f2bf(grd);
            }
        }
        __syncthreads();
        // ---- per-wave GEMM (one 32-wide k-step): feat[o][px] += W[o][c]*E[px][c] ----
        {
            const int cg = quad * 8;    // k-offset within chunk
            bf16x8 bfr[4];
#pragma unroll
            for (int nt = 0; nt < 4; ++nt)
                bfr[nt] = *(const bf16x8*)&El[(wv * 64 + nt * 16 + l15) * ELS + cg];
#pragma unroll
            for (int mt = 0; mt < 8; ++mt) {
                // pre-converted bf16 weights: no per-iter cvt VALU
                bf16x8 a = *(const bf16x8*)&wBb[(size_t)(wv * 128 + mt * 16 + l15) * 512 + cbase + cg];
#pragma unroll
                for (int nt = 0; nt < 4; ++nt)
                    acc[mt][nt] = __builtin_amdgcn_mfma_f32_16x16x32_bf16(a, bfr[nt], acc[mt][nt], 0, 0, 0);
            }
        }
        __syncthreads();
    }
    // ---- epilogue: BN(eval) + GELU, pooled partials, LDS-restaged coalesced stores ----
    const int pixbase = h * 128 + w0;
    float* wbuf = stg + wv * 1056;     // per-wave 16 rows * 66 fp32 (stride 66 -> 2-way free)
#pragma unroll 1
    for (int mt = 0; mt < 8; ++mt) {
        const int ob = wv * 128 + mt * 16 + quad * 4;   // concat channel base for 4 regs
        float s[4], sh[4], ps[4];
#pragma unroll
        for (int r = 0; r < 4; ++r) {
            float sc = bg[ob + r] * 0.9999950000374997f;   // 1/sqrt(1+1e-5)
            s[r] = sc; sh[r] = bB[ob + r] * sc + bbt[ob + r]; ps[r] = 0.f;
        }
#pragma unroll
        for (int nt = 0; nt < 4; ++nt) {
            const int px = nt * 16 + l15;
#pragma unroll
            for (int r = 0; r < 4; ++r) {
                float y = acc[mt][nt][r] * s[r] + sh[r];
                float f = gelu_f(y);
                ps[r] += f;
                wbuf[(quad * 4 + r) * 66 + px] = f;    // LDS restage (wave-private)
            }
        }
#pragma unroll
        for (int r = 0; r < 4; ++r)
#pragma unroll
            for (int off = 1; off < 16; off <<= 1)
                ps[r] += __shfl_xor(ps[r], off, 64);
        if (l15 == 0) {
#pragma unroll
            for (int r = 0; r < 4; ++r)
                atomicAdd(&pooled[b * 512 + ob + r], ps[r]);
        }
        // 16 channel rows, each one full-wave-contiguous 256 B dword store
        const size_t rowbase = (size_t)(b * 512 + wv * 128 + mt * 16) * 16384 + pixbase;
#pragma unroll
        for (int j = 0; j < 16; ++j)
            ef[rowbase + (size_t)j * 16384 + lane] = wbuf[j * 66 + lane];
    }
}

// ---------------- K2: SE attention (tiny, fp32) ----------------
__global__ void k2_att(const float* __restrict__ pooled,
                       const float* __restrict__ w1, const float* __restrict__ b1,
                       const float* __restrict__ w2, const float* __restrict__ b2,
                       float* __restrict__ att)
{
    __shared__ float pl[2048];
    __shared__ float hb[256];
    const int t = threadIdx.x;
    for (int i = t; i < 2048; i += 256) pl[i] = pooled[i] * (1.0f / 16384.0f);
    __syncthreads();
    {
        const int bb = t >> 6, e = t & 63;
        float a = b1[e];
        const float* wr = w1 + e * 512;
        for (int c = 0; c < 512; ++c)
            a += pl[bb * 512 + c] * wr[c];
        hb[t] = gelu_f(a);
    }
    __syncthreads();
    for (int i = t; i < 2048; i += 256) {
        const int bb = i >> 9, c = i & 511;
        const float* wr = w2 + c * 64;
        float a = b2[c];
        for (int e = 0; e < 64; ++e)
            a += hb[bb * 64 + e] * wr[e];
        att[i] = 1.0f / (1.0f + __expf(-a));
    }
}

// ---------------- K3: coalesced stage -> LDS bf16 transpose, GEMM + LN + GELU + residual ----------------
#define L3W 260   // U32 per LDS pixel row (256 c-pairs + 4 pad; 1040 B)

__global__ __launch_bounds__(256, 2)
void k3_fuse(const float* __restrict__ ef, const float* __restrict__ att,
             const U16* __restrict__ wfb, const float* __restrict__ bfu,
             const float* __restrict__ lng, const float* __restrict__ lnb,
             const float* __restrict__ x, float* __restrict__ out)
{
    __shared__ U32 sh32[64 * L3W];          // 66560 B
    __shared__ float red_s[256];
    __shared__ float red_q[256];
    __shared__ float mu_s[64];
    __shared__ float iv_s[64];
    const int tid  = threadIdx.x, bi = blockIdx.x;
    const int b    = bi >> 8;
    const int pix0 = (bi & 255) << 6;
    const int lane = tid & 63, wv = tid >> 6;
    const int l15  = lane & 15, quad = lane >> 4;

    // ---- stage: cooperative ROW-WISE reads of ef [b][c][pix] (one instr = one
    //      contiguous 256 B row segment, lane = pixel), scale by att, bf16-pack,
    //      transpose into LDS [px][c-pair]. Wave wv owns pairs [wv*64, wv*64+64).
#pragma unroll 4
    for (int i = 0; i < 32; ++i) {
        const int p  = wv * 64 + 2 * i;        // 2 pairs (4 channels) per iter
        const int c0 = 2 * p;
        const float* rp = ef + (size_t)(b * 512 + c0) * 16384 + pix0 + lane;
        float v0 = rp[0];
        float v1 = rp[16384];
        float v2 = rp[2 * 16384];
        float v3 = rp[3 * 16384];
        const float a0 = att[b * 512 + c0];
        const float a1 = att[b * 512 + c0 + 1];
        const float a2 = att[b * 512 + c0 + 2];
        const float a3 = att[b * 512 + c0 + 3];
        U32 wlo = (U32)f2bf(v0 * a0) | ((U32)f2bf(v1 * a1) << 16);
        U32 whi = (U32)f2bf(v2 * a2) | ((U32)f2bf(v3 * a3) << 16);
        uint2 pk; pk.x = wlo; pk.y = whi;
        *(uint2*)&sh32[lane * L3W + p] = pk;   // ds_write_b64 (p even -> 8B aligned)
    }
    __syncthreads();

    f32x4 acc[4][8];
#pragma unroll
    for (int i = 0; i < 4; ++i)
#pragma unroll
        for (int j = 0; j < 8; ++j) {
            f32x4 z = {0.f, 0.f, 0.f, 0.f};
            acc[i][j] = z;
        }
#pragma unroll 1
    for (int ks = 0; ks < 16; ++ks) {
        const int cg = ks * 32 + quad * 8;
        bf16x8 a[4];
#pragma unroll
        for (int mt = 0; mt < 4; ++mt)
            a[mt] = *(const bf16x8*)&sh32[(mt * 16 + l15) * L3W + (cg >> 1)];
#pragma unroll
        for (int nt = 0; nt < 8; ++nt) {
            // pre-converted bf16 weights
            bf16x8 bw = *(const bf16x8*)&wfb[(size_t)(wv * 128 + nt * 16 + l15) * 512 + cg];
#pragma unroll
            for (int mt = 0; mt < 4; ++mt)
                acc[mt][nt] = __builtin_amdgcn_mfma_f32_16x16x32_bf16(a[mt], bw, acc[mt][nt], 0, 0, 0);
        }
    }
    // bias then LN stats (sum, sumsq over all 512 channels per pixel)
#pragma unroll
    for (int nt = 0; nt < 8; ++nt) {
        const float bz = bfu[wv * 128 + nt * 16 + l15];
#pragma unroll
        for (int mt = 0; mt < 4; ++mt)
#pragma unroll
            for (int r = 0; r < 4; ++r)
                acc[mt][nt][r] += bz;
    }
#pragma unroll
    for (int mt = 0; mt < 4; ++mt)
#pragma unroll
        for (int r = 0; r < 4; ++r) {
            float s = 0.f, q = 0.f;
#pragma unroll
            for (int nt = 0; nt < 8; ++nt) {
                float v = acc[mt][nt][r];
                s += v; q += v * v;
            }
#pragma unroll
            for (int off = 1; off < 16; off <<= 1) {
                s += __shfl_xor(s, off, 64);
                q += __shfl_xor(q, off, 64);
            }
            if (l15 == 0) {
                const int p = mt * 16 + quad * 4 + r;
                red_s[p * 4 + wv] = s;
                red_q[p * 4 + wv] = q;
            }
        }
    __syncthreads();
    if (tid < 64) {
        float S = red_s[tid * 4] + red_s[tid * 4 + 1] + red_s[tid * 4 + 2] + red_s[tid * 4 + 3];
        float Q = red_q[tid * 4] + red_q[tid * 4 + 1] + red_q[tid * 4 + 2] + red_q[tid * 4 + 3];
        float mu  = S * (1.0f / 512.0f);
        float var = fmaxf(Q * (1.0f / 512.0f) - mu * mu, 0.0f);
        mu_s[tid] = mu;
        iv_s[tid] = rsqrtf(var + 1e-6f);
    }
    __syncthreads();
    // ---- epilogue: LN + GELU into per-wave LDS restage (aliases sh32, dead after
    //      GEMM+barrier), then row-wise contiguous x loads + out stores ----
    float* ebuf = (float*)sh32 + wv * 1072;    // 16 rows * 67 fp32 per wave
#pragma unroll 1
    for (int nt = 0; nt < 8; ++nt) {
        const int o = wv * 128 + nt * 16 + l15;
        const float g  = lng[o];
        const float be = lnb[o];
#pragma unroll
        for (int mt = 0; mt < 4; ++mt) {
#pragma unroll
            for (int r = 0; r < 4; ++r) {
                const int p = mt * 16 + quad * 4 + r;
                float z = (acc[mt][nt][r] - mu_s[p]) * iv_s[p];
                float y = z * g + be;
                ebuf[l15 * 67 + p] = gelu_f(y);    // LDS restage (wave-private)
            }
        }
        const size_t rowbase = (size_t)(b * 512 + wv * 128 + nt * 16) * 16384 + pix0;
#pragma unroll
        for (int j = 0; j < 16; ++j) {
            float v = ebuf[j * 67 + lane] + x[rowbase + (size_t)j * 16384 + lane];
            out[rowbase + (size_t)j * 16384 + lane] = v;
        }
    }
}

extern "C" void kernel_launch(void* const* d_in, const int* in_sizes, int n_in,
                              void* d_out, int out_size, void* d_ws, size_t ws_size,
                              hipStream_t stream)
{
    const float* x   = (const float*)d_in[0];
    const float* wB  = (const float*)d_in[1];
    const float* bB  = (const float*)d_in[2];
    const float* bg  = (const float*)d_in[3];
    const float* bbt = (const float*)d_in[4];
    const float* w1  = (const float*)d_in[5];
    const float* b1  = (const float*)d_in[6];
    const float* w2  = (const float*)d_in[7];
    const float* b2  = (const float*)d_in[8];
    const float* wf  = (const float*)d_in[9];
    const float* bfu = (const float*)d_in[10];
    const float* lng = (const float*)d_in[11];
    const float* lnb = (const float*)d_in[12];
    float* out = (float*)d_out;

    // ef intermediate (fp32, [b][c][pix] == output layout) lives in d_out:
    // K3 blocks read exactly the region they later overwrite (in-place safe).
    // d_ws: pooled 8K | att 8K | wB bf16 512K | wf bf16 512K  (~1.04 MiB)
    float* ef     = out;
    float* pooled = (float*)d_ws;
    float* att    = (float*)((char*)d_ws + 8192);
    U16*   wBb    = (U16*)((char*)d_ws + 16384);
    U16*   wfb    = (U16*)((char*)d_ws + 16384 + 524288);

    hipMemsetAsync(pooled, 0, 2048 * sizeof(float), stream);
    hipLaunchKernelGGL(k0_cvt, dim3(1024), dim3(256), 0, stream, wB, wf, wBb, wfb);
    hipLaunchKernelGGL(k1_branch, dim3(1024), dim3(256), 0, stream,
                       x, wBb, bB, bg, bbt, ef, pooled);
    hipLaunchKernelGGL(k2_att, dim3(1), dim3(256), 0, stream,
                       pooled, w1, b1, w2, b2, att);
    hipLaunchKernelGGL(k3_fuse, dim3(1024), dim3(256), 0, stream,
                       ef, att, wfb, bfu, lng, lnb, x, out);
}